// Round 11
// baseline (160.958 us; speedup 1.0000x reference)
//
#include <hip/hip_runtime.h>
#include <math.h>

#define TPB 256

// Problem constants
constexpr int Bc = 16, Tc = 1536;
constexpr int T2c = 192;           // T / P1
constexpr float EPSc = 1e-5f;
constexpr float NSLOPE = 0.2f;
constexpr int MDI = 16;            // padded in-degree stride (bytes); byte15 = indeg
constexpr int MDO = 8;             // padded out-degree stride (bytes)
constexpr float L2E = 1.4426950408889634f;

// r11: TILE = 16 output t's per block (was 8). 47 x-rows + ones row = 48.
constexpr int TILE = 16;
constexpr int ROWS = 48;

typedef float vf2 __attribute__((ext_vector_type(2)));

// Workspace layout (float offsets)
constexpr int OW_WEFF = 0;         // [32 k][32 f2]
constexpr int OW_CHL  = 1024;      // [32] (prep-internal; folded into c2)
constexpr int OW_CES  = 1056;      // [4 h][2] {ces,ced} interleaved
constexpr int OW_WSD  = 1064;      // [4 h][32 k][2] {wes,wed} interleaved
constexpr int OW_A2C2 = 1320;      // a2[32] | c2[32] (chl+gat-bias folded)
constexpr int OW_WFT  = 1384;      // [32 f2][32 k]  transposed weff
constexpr int OW_GRAPH= 2408;      // 417 ints packed byte graph (gat reads GLOBAL)
constexpr int OW_P    = 2825;      // [B][192][32]

// gat LDS layout (float offsets)
constexpr int L_XT  = 0;           // xT [48 c][68 v]; row 47 = ones; ROTATION-SWIZZLED
constexpr int L_WB  = 3264;        // [4 h][1088]: wb rows [16 t][68 v];
                                   //   B scratch = 4 x 256-float slices (s*272);
                                   //   after C: Y overlay [16 t][49] (wave-local)
constexpr int L_TOT = 7616;        // 30.5 KB -> 5 blocks/CU

#define LGKM0() __asm__ volatile("s_waitcnt lgkmcnt(0)" ::: "memory")

// XT swizzle: column granule rotated by row: g' = (g + row) & 15.
__device__ __forceinline__ int xt_idx(int row, int g, int lo)
{
    return L_XT + row * 68 + (((g + row) & 15) << 2) + lo;
}

// exp2(leaky(z)) with logit pre-scaled by log2(e)
__device__ __forceinline__ float lexp2(float z)
{
    return __builtin_amdgcn_exp2f(fmaxf(z, NSLOPE * z));
}

// Butterfly sums via gfx950 permlane-swap builtins (VALU pipe; proven r6-r10).
__device__ __forceinline__ float bfly16_sum(float s)
{
#if __has_builtin(__builtin_amdgcn_permlane16_swap)
    unsigned u = __builtin_bit_cast(unsigned, s);
    auto r = __builtin_amdgcn_permlane16_swap(u, u, false, false);
    return __builtin_bit_cast(float, (unsigned)r[0]) +
           __builtin_bit_cast(float, (unsigned)r[1]);
#else
    return s + __shfl_xor(s, 16);
#endif
}

__device__ __forceinline__ float bfly32_sum(float s)
{
#if __has_builtin(__builtin_amdgcn_permlane32_swap)
    unsigned u = __builtin_bit_cast(unsigned, s);
    auto r = __builtin_amdgcn_permlane32_swap(u, u, false, false);
    return __builtin_bit_cast(float, (unsigned)r[0]) +
           __builtin_bit_cast(float, (unsigned)r[1]);
#else
    return s + __shfl_xor(s, 32);
#endif
}

// ---------------------------------------------------------------------------
// Prep (1 block) — unchanged (verified r7-r10).
// ---------------------------------------------------------------------------
__global__ void prep_kernel(const float* __restrict__ c1w,
                            const float* __restrict__ g1, const float* __restrict__ b1,
                            const float* __restrict__ m1, const float* __restrict__ v1,
                            const float* __restrict__ W,
                            const float* __restrict__ asrc, const float* __restrict__ adst,
                            const float* __restrict__ bias,
                            const float* __restrict__ g2, const float* __restrict__ b2,
                            const float* __restrict__ m2, const float* __restrict__ v2,
                            const int* __restrict__ ei, int ne, float* __restrict__ ws)
{
    const int tid = threadIdx.x;
    __shared__ float sweff[1024];
    __shared__ float schl[32];
    __shared__ int isrcp_i[64 * MDI];
    __shared__ int outdst_i[64 * MDO];
    __shared__ int inslot[64], outslot[64];

    for (int idx = tid; idx < 1024; idx += TPB) {
        int k = idx >> 5, f2 = idx & 31;
        float s = 0.f;
        for (int f = 0; f < 16; f++) {
            float a1 = g1[f] * rsqrtf(v1[f] + EPSc);
            s += a1 * W[f * 32 + f2] * c1w[f * 32 + k];
        }
        ws[OW_WEFF + idx] = s;
        ws[OW_WFT + f2 * 32 + k] = s;
        sweff[idx] = s;
    }
    for (int f2 = tid; f2 < 32; f2 += TPB) {
        float s = 0.f;
        for (int f = 0; f < 16; f++) {
            float a1 = g1[f] * rsqrtf(v1[f] + EPSc);
            s = fmaf(b1[f] - a1 * m1[f], W[f * 32 + f2], s);
        }
        ws[OW_CHL + f2] = s;
        schl[f2] = s;
        float a2 = g2[f2] * rsqrtf(v2[f2] + EPSc);
        ws[OW_A2C2 + f2] = a2;
        // bn2 shift with gat bias AND chl (rowsum==64 exactly) folded in
        ws[OW_A2C2 + 32 + f2] = b2[f2] + a2 * (bias[f2] - m2[f2] + s);
    }

    // graph lists WITHOUT self-edges (self handled in-register in gat)
    for (int i = tid; i < 64 * MDI; i += TPB) isrcp_i[i] = 0;
    for (int i = tid; i < 64 * MDO; i += TPB) outdst_i[i] = 0;
    if (tid < 64) { inslot[tid] = 0; outslot[tid] = 0; }
    __syncthreads();
    for (int e = tid; e < ne; e += TPB) {
        int s = ei[e], d = ei[ne + e];
        if (s == d) continue;
        int pi = atomicAdd(&inslot[d], 1);
        if (pi < 15) isrcp_i[d * MDI + pi] = s;
        int po = atomicAdd(&outslot[s], 1);
        if (po < MDO) outdst_i[s * MDO + po] = d;
    }
    __syncthreads();

    // {wes,wed} interleaved pairs + {ces,ced} pairs
    if (tid < 128) {
        int k = tid >> 2, h = tid & 3;
        float s1 = 0.f, s2 = 0.f;
        for (int o = 0; o < 8; o++) {
            float wv = sweff[k * 32 + h * 8 + o];
            s1 = fmaf(asrc[h * 8 + o], wv, s1);
            s2 = fmaf(adst[h * 8 + o], wv, s2);
        }
        ws[OW_WSD + h * 64 + k * 2]     = s1;
        ws[OW_WSD + h * 64 + k * 2 + 1] = s2;
    }
    if (tid < 4) {
        float s1 = 0.f, s2 = 0.f;
        for (int o = 0; o < 8; o++) {
            float cv = schl[tid * 8 + o];
            s1 = fmaf(asrc[tid * 8 + o], cv, s1);
            s2 = fmaf(adst[tid * 8 + o], cv, s2);
        }
        ws[OW_CES + tid * 2]     = s1;
        ws[OW_CES + tid * 2 + 1] = s2;
    }
    // pack graph to bytes
    unsigned char* gb = (unsigned char*)(ws + OW_GRAPH);
    for (int i = tid; i < 64 * MDI; i += TPB) gb[i] = (unsigned char)isrcp_i[i];
    for (int i = tid; i < 64 * MDO; i += TPB) gb[1088 + i] = (unsigned char)outdst_i[i];
    __syncthreads();
    if (tid < 64) {
        int id = inslot[tid] < 15 ? inslot[tid] : 15;
        int od = outslot[tid] < MDO ? outslot[tid] : MDO;
        gb[tid * MDI + 15] = (unsigned char)id;   // indeg packed into list byte 15
        gb[1024 + tid] = (unsigned char)id;
        gb[1600 + tid] = (unsigned char)od;
    }
    __syncthreads();
    if (tid == 0) {
        int mi = 0;
        for (int d = 0; d < 64; d++) {
            int a = gb[1024 + d];
            mi = a > mi ? a : mi;
        }
        gb[1664] = (unsigned char)mi;
        gb[1665] = 0;
    }
}

// ---------------------------------------------------------------------------
// Fused conv1+bn1+GAT + mean(v) + bn2+elu+pool8.  wave = head, lane = node.
// r11: 16-t tile. Per-output fixed costs (S halo, barrier, B fences) halved.
// ONE barrier total (after S); everything downstream is wave-local:
//   B scratch + wb rows + Y overlay all live in the own-head 1088-float
//   L_WB slice (in-order DS makes write-after-read safe without fences).
// ---------------------------------------------------------------------------
__global__ __launch_bounds__(TPB, 4) void gat_kernel(
    const float* __restrict__ x,
    const float* __restrict__ wfTp,
    const float* __restrict__ cesg,
    const float* __restrict__ wsdg,
    const float* __restrict__ a2c2,
    const int* __restrict__ graphi,
    float* __restrict__ pout)
{
    __shared__ __align__(16) float sm[L_TOT];

    const int tid   = threadIdx.x;
    const int b     = blockIdx.x / 96;
    const int tile2 = blockIdx.x % 96;
    const int t0    = tile2 * TILE;

    const int h = tid >> 6, v = tid & 63;   // wave = head, lane = node

    // ---- graph loads from global, issued EARLY (latency hides under S+A) --
    const unsigned char* gbg = (const unsigned char*)graphi;
    const int4 il = *(const int4*)(gbg + v * MDI);                // in-list + indeg
    const unsigned ow = *(const unsigned*)(gbg + 1088 + v * MDO); // 4 KNN dsts
    const int mdin = __builtin_amdgcn_readfirstlane(((const int*)graphi)[416] & 0xFF);

    // ---- S: stage xT (coalesced global, swizzled LDS writes; 12 iters) ----
    for (int idx = tid; idx < ROWS * 64; idx += TPB) {
        const int vv = idx / ROWS, j = idx % ROWS;
        float val = 1.0f;
        if (j < 47) {
            const int t = t0 - 15 + j;
            val = (t >= 0 && t < Tc) ? x[(b * 64 + vv) * Tc + t] : 0.f;
        }
        sm[xt_idx(j, vv >> 2, vv & 3)] = val;
    }
    __syncthreads();   // the ONLY block-wide barrier

    const int hs = __builtin_amdgcn_readfirstlane(h);
    const vf2* wsdh = (const vf2*)(wsdg + hs * 64);   // uniform -> s_load pairs

    // ---- Phase A: es/ed convs for 16 t's, {es,ed} packed accumulators ----
    float aes[16], aed[16];
    {
        const int g = v >> 2, lo = v & 3;
        const vf2 cv = *(const vf2*)(cesg + hs * 2);
        vf2 acc2[16];
        #pragma unroll
        for (int t = 0; t < 16; t++) acc2[t] = cv;
        float xr[16];
        #pragma unroll
        for (int q = 0; q < 15; q++) xr[q] = sm[xt_idx(q, g, lo)];
        #pragma unroll
        for (int k = 0; k < 32; k++) {
            xr[(k + 15) & 15] = sm[xt_idx(k + 15, g, lo)];
            const vf2 wk = wsdh[k];                  // {wes_k, wed_k} SGPR pair
            #pragma unroll
            for (int t = 0; t < 16; t++) {
                const float xv = xr[(k + t) & 15];
                acc2[t] += (vf2){xv, xv} * wk;       // v_pk_fma_f32 (splat)
            }
        }
        #pragma unroll
        for (int t = 0; t < 16; t++) {
            aes[t] = acc2[t].x * L2E;                // exp2-domain prescale
            aed[t] = acc2[t].y * L2E;
        }
    }

    // ---- Phase B: softmax via quad-scratch wide-LDS gather (6 fences) ----
    {
        float* scr0 = &sm[L_WB + h * 1088];
        float* scr1 = &sm[L_WB + h * 1088 + 272];
        float* scr2 = &sm[L_WB + h * 1088 + 544];
        float* scr3 = &sm[L_WB + h * 1088 + 816];

        const int indeg = (int)(((unsigned)il.w) >> 24);
        const unsigned iw[4] = {(unsigned)il.x, (unsigned)il.y,
                                (unsigned)il.z, (unsigned)il.w};

        // self-edge term
        float den[16], Eself[16];
        #pragma unroll
        for (int t = 0; t < 16; t++) {
            Eself[t] = lexp2(aes[t] + aed[t]);
            den[t] = Eself[t];
        }

        // in-gather: all 16 t's staged; one drain; 4 b128 reads per edge
        *(float4*)(scr0 + v * 4) = (float4){aes[0],  aes[1],  aes[2],  aes[3]};
        *(float4*)(scr1 + v * 4) = (float4){aes[4],  aes[5],  aes[6],  aes[7]};
        *(float4*)(scr2 + v * 4) = (float4){aes[8],  aes[9],  aes[10], aes[11]};
        *(float4*)(scr3 + v * 4) = (float4){aes[12], aes[13], aes[14], aes[15]};
        LGKM0();
        #pragma unroll
        for (int e = 0; e < 15; e++) {
            if (e < mdin) {                  // wave-uniform bound
                const int s = (int)((iw[e >> 2] >> ((e & 3) * 8)) & 0xFF);
                const float4 ea = *(const float4*)(scr0 + s * 4);
                const float4 eb = *(const float4*)(scr1 + s * 4);
                const float4 ec = *(const float4*)(scr2 + s * 4);
                const float4 ed = *(const float4*)(scr3 + s * 4);
                const float valid = (e < indeg) ? 1.f : 0.f;
                den[0]  += valid * lexp2(ea.x + aed[0]);
                den[1]  += valid * lexp2(ea.y + aed[1]);
                den[2]  += valid * lexp2(ea.z + aed[2]);
                den[3]  += valid * lexp2(ea.w + aed[3]);
                den[4]  += valid * lexp2(eb.x + aed[4]);
                den[5]  += valid * lexp2(eb.y + aed[5]);
                den[6]  += valid * lexp2(eb.z + aed[6]);
                den[7]  += valid * lexp2(eb.w + aed[7]);
                den[8]  += valid * lexp2(ec.x + aed[8]);
                den[9]  += valid * lexp2(ec.y + aed[9]);
                den[10] += valid * lexp2(ec.z + aed[10]);
                den[11] += valid * lexp2(ec.w + aed[11]);
                den[12] += valid * lexp2(ed.x + aed[12]);
                den[13] += valid * lexp2(ed.y + aed[13]);
                den[14] += valid * lexp2(ed.z + aed[14]);
                den[15] += valid * lexp2(ed.w + aed[15]);
            }
        }
        LGKM0();

        float rden[16], wb[16];
        #pragma unroll
        for (int t = 0; t < 16; t++) {
            float r = __builtin_amdgcn_rcpf(den[t]);
            r = r * (2.f - den[t] * r);
            rden[t] = r;
            wb[t] = Eself[t] * r;
        }

        // out-gather: 2 rounds x 8 t's; {ed,ed,rden,rden} quads in 4 scratches
        #pragma unroll
        for (int r2 = 0; r2 < 2; r2++) {
            const int tb = r2 * 8;
            *(float4*)(scr0 + v * 4) = (float4){aed[tb + 0], aed[tb + 1],
                                                rden[tb + 0], rden[tb + 1]};
            *(float4*)(scr1 + v * 4) = (float4){aed[tb + 2], aed[tb + 3],
                                                rden[tb + 2], rden[tb + 3]};
            *(float4*)(scr2 + v * 4) = (float4){aed[tb + 4], aed[tb + 5],
                                                rden[tb + 4], rden[tb + 5]};
            *(float4*)(scr3 + v * 4) = (float4){aed[tb + 6], aed[tb + 7],
                                                rden[tb + 6], rden[tb + 7]};
            LGKM0();
            #pragma unroll
            for (int j = 0; j < 4; j++) {
                const int d = (int)((ow >> (j * 8)) & 0xFF);
                const float4 g0 = *(const float4*)(scr0 + d * 4);
                const float4 g1 = *(const float4*)(scr1 + d * 4);
                const float4 g2 = *(const float4*)(scr2 + d * 4);
                const float4 g3 = *(const float4*)(scr3 + d * 4);
                wb[tb + 0] = fmaf(lexp2(aes[tb + 0] + g0.x), g0.z, wb[tb + 0]);
                wb[tb + 1] = fmaf(lexp2(aes[tb + 1] + g0.y), g0.w, wb[tb + 1]);
                wb[tb + 2] = fmaf(lexp2(aes[tb + 2] + g1.x), g1.z, wb[tb + 2]);
                wb[tb + 3] = fmaf(lexp2(aes[tb + 3] + g1.y), g1.w, wb[tb + 3]);
                wb[tb + 4] = fmaf(lexp2(aes[tb + 4] + g2.x), g2.z, wb[tb + 4]);
                wb[tb + 5] = fmaf(lexp2(aes[tb + 5] + g2.y), g2.w, wb[tb + 5]);
                wb[tb + 6] = fmaf(lexp2(aes[tb + 6] + g3.x), g3.z, wb[tb + 6]);
                wb[tb + 7] = fmaf(lexp2(aes[tb + 7] + g3.y), g3.w, wb[tb + 7]);
            }
            LGKM0();
        }

        // wb stores land after scratch is dead (all reads drained)
        #pragma unroll
        for (int t = 0; t < 16; t++)
            sm[L_WB + h * 1088 + t * 68 + v] = wb[t];
    }
    LGKM0();   // wave-local drain before C reads own-head wb rows

    // ---- Phase C: y[t,c] = sum_v wb[t,v]*xT[c,v], 2 reps of 8 t-rows
    //      lane = (cg 8) x (th 2) x (kq 4): 6c x 2t x 16v per lane/rep
    //      Y rows [16][49] overlay own-head WB region (in-order DS safe) ----
    {
        const int cg = v & 7;
        const int th = (v >> 3) & 1;
        const int kq = v >> 4;

        #pragma unroll
        for (int rep = 0; rep < 2; rep++) {
            vf2 yp[4][6];
            #pragma unroll
            for (int i = 0; i < 4; i++)
                #pragma unroll
                for (int q = 0; q < 6; q++) yp[i][q] = (vf2){0.f, 0.f};

            const float* wbbase = &sm[L_WB + h * 1088 + (rep * 8 + th * 4) * 68];
            #pragma unroll
            for (int v4 = 0; v4 < 4; v4++) {
                const int vcol = kq * 16 + v4 * 4;
                float4 wrow[4];
                #pragma unroll
                for (int i = 0; i < 4; i++)
                    wrow[i] = *(const float4*)(wbbase + i * 68 + vcol);
                #pragma unroll
                for (int q = 0; q < 6; q++) {
                    const int row = cg * 6 + q;
                    const int mg = ((kq * 4 + v4 + row) & 15) << 2;   // swizzled
                    const float4 x4 = *(const float4*)(&sm[L_XT + row * 68 + mg]);
                    const vf2 x01 = (vf2){x4.x, x4.y}, x23 = (vf2){x4.z, x4.w};
                    #pragma unroll
                    for (int i = 0; i < 4; i++) {
                        const vf2 w01 = (vf2){wrow[i].x, wrow[i].y};
                        const vf2 w23 = (vf2){wrow[i].z, wrow[i].w};
                        yp[i][q] += w01 * x01;          // v_pk_fma_f32
                        yp[i][q] += w23 * x23;
                    }
                }
            }
            float ya[4][6];
            #pragma unroll
            for (int i = 0; i < 4; i++)
                #pragma unroll
                for (int q = 0; q < 6; q++) {
                    float s = yp[i][q].x + yp[i][q].y;
                    ya[i][q] = bfly32_sum(bfly16_sum(s));
                }
            // write Y row rep*8 + th*4 + kq, cols cg*6..cg*6+5 (stride 49)
            float* yw = &sm[L_WB + h * 1088 + (rep * 8 + th * 4 + kq) * 49 + cg * 6];
            #pragma unroll
            for (int q = 0; q < 6; q++) {
                float a01 = (kq & 1) ? ya[1][q] : ya[0][q];
                float a23 = (kq & 1) ? ya[3][q] : ya[2][q];
                yw[q] = (kq & 2) ? a23 : a01;
            }
        }
    }
    LGKM0();   // wave-local: D reads only own-head Y rows

    // ---- Phase D+E fused (wave-local): g -> bn2+elu -> pool8, 2 outputs ----
    {
        const int t = v >> 3, o = v & 7;
        const int f2d = h * 8 + o;
        const float4* wf4 = (const float4*)(wfTp + f2d * 32);
        const float a2 = a2c2[f2d], c2 = a2c2[32 + f2d];

        #pragma unroll
        for (int po = 0; po < 2; po++) {
            const int tt = po * 8 + t;
            const float* yr = &sm[L_WB + h * 1088 + tt * 49];
            float acc = 0.f;                 // chl folded into c2 (rowsum==64)
            #pragma unroll
            for (int k4 = 0; k4 < 8; k4++) {
                const float4 w = wf4[k4];
                acc = fmaf(w.x, yr[tt + 4 * k4 + 0],
                      fmaf(w.y, yr[tt + 4 * k4 + 1],
                      fmaf(w.z, yr[tt + 4 * k4 + 2],
                      fmaf(w.w, yr[tt + 4 * k4 + 3], acc))));
            }
            float y = fmaf(a2, acc * (1.f / 64.f), c2);
            y = y > 0.f ? y : __expf(y) - 1.f;
            y += __shfl_xor(y, 8);
            y = bfly32_sum(bfly16_sum(y));
            if (v < 8)
                pout[(b * T2c + tile2 * 2 + po) * 32 + h * 8 + v] = y * 0.125f;
        }
    }
}

// ---------------------------------------------------------------------------
// conv3(K=16,'same') + bn3 + elu + avgpool(4): p[B,192,32] -> out[B,32,48].
// ---------------------------------------------------------------------------
__global__ __launch_bounds__(TPB) void conv3_kernel(const float* __restrict__ pp,
                                                    const float* __restrict__ w3,
                                                    const float* __restrict__ g3,
                                                    const float* __restrict__ b3,
                                                    const float* __restrict__ m3,
                                                    const float* __restrict__ v3,
                                                    float* __restrict__ outp)
{
    __shared__ float pl[63 * 32];
    __shared__ float q[48 * 32];
    const int tid = threadIdx.x;
    const int b = blockIdx.x >> 2, cc = blockIdx.x & 3;

    for (int idx = tid; idx < 63 * 32; idx += TPB) {
        int r = idx >> 5, f2 = idx & 31;
        int tog = cc * 48 - 7 + r;
        pl[idx] = (tog >= 0 && tog < T2c) ? pp[(b * T2c + tog) * 32 + f2] : 0.f;
    }
    __syncthreads();

    const int f2o = tid & 31, grp = tid >> 5;
    const int tb = grp * 6;
    float acc[6] = { 0.f, 0.f, 0.f, 0.f, 0.f, 0.f };
    for (int f2i = 0; f2i < 32; f2i++) {
        float seg[21];
        #pragma unroll
        for (int r = 0; r < 21; r++) seg[r] = pl[(tb + r) * 32 + f2i];
        const float4* wrow = (const float4*)(w3 + (f2o * 32 + f2i) * 16);
        #pragma unroll
        for (int k4 = 0; k4 < 4; k4++) {
            const float4 w4 = wrow[k4];
            #pragma unroll
            for (int j = 0; j < 6; j++) {
                acc[j] = fmaf(seg[j + k4 * 4 + 0], w4.x,
                         fmaf(seg[j + k4 * 4 + 1], w4.y,
                         fmaf(seg[j + k4 * 4 + 2], w4.z,
                         fmaf(seg[j + k4 * 4 + 3], w4.w, acc[j]))));
            }
        }
    }
    const float a3 = g3[f2o] * rsqrtf(v3[f2o] + EPSc);
    const float c3 = b3[f2o] - a3 * m3[f2o];
    #pragma unroll
    for (int j = 0; j < 6; j++) {
        float y = fmaf(a3, acc[j], c3);
        y = y > 0.f ? y : __expf(y) - 1.f;
        q[(tb + j) * 32 + f2o] = y;
    }
    __syncthreads();
    for (int idx = tid; idx < 12 * 32; idx += TPB) {
        int t4 = idx >> 5, f2 = idx & 31;
        int r0 = t4 * 4;
        float s = q[r0 * 32 + f2] + q[(r0 + 1) * 32 + f2] +
                  q[(r0 + 2) * 32 + f2] + q[(r0 + 3) * 32 + f2];
        outp[(b * 32 + f2) * 48 + cc * 12 + t4] = s * 0.25f;
    }
}

// ---------------------------------------------------------------------------
extern "C" void kernel_launch(void* const* d_in, const int* in_sizes, int n_in,
                              void* d_out, int out_size, void* d_ws, size_t ws_size,
                              hipStream_t stream)
{
    const float* x    = (const float*)d_in[0];
    const float* c1w  = (const float*)d_in[1];
    const float* g1   = (const float*)d_in[2];
    const float* b1   = (const float*)d_in[3];
    const float* m1   = (const float*)d_in[4];
    const float* v1   = (const float*)d_in[5];
    const float* W    = (const float*)d_in[6];
    const float* asrc = (const float*)d_in[7];
    const float* adst = (const float*)d_in[8];
    const float* bias = (const float*)d_in[9];
    const float* g2   = (const float*)d_in[10];
    const float* b2   = (const float*)d_in[11];
    const float* m2   = (const float*)d_in[12];
    const float* v2   = (const float*)d_in[13];
    const float* w3   = (const float*)d_in[14];
    const float* g3   = (const float*)d_in[15];
    const float* b3   = (const float*)d_in[16];
    const float* m3   = (const float*)d_in[17];
    const float* v3   = (const float*)d_in[18];
    const int*   ei   = (const int*)d_in[19];
    const int    ne   = in_sizes[19] / 2;

    float* ws = (float*)d_ws;

    prep_kernel<<<1, TPB, 0, stream>>>(c1w, g1, b1, m1, v1, W, asrc, adst,
                                       bias, g2, b2, m2, v2, ei, ne, ws);

    gat_kernel<<<Bc * 96, TPB, 0, stream>>>(x,
                                            ws + OW_WFT,
                                            ws + OW_CES,
                                            ws + OW_WSD,
                                            ws + OW_A2C2,
                                            (const int*)(ws + OW_GRAPH),
                                            ws + OW_P);

    conv3_kernel<<<Bc * 4, TPB, 0, stream>>>(ws + OW_P, w3, g3, b3, m3, v3,
                                             (float*)d_out);
}

// Round 12
// 156.405 us; speedup vs baseline: 1.0291x; 1.0291x over previous
//
#include <hip/hip_runtime.h>
#include <math.h>

#define TPB 256

// Problem constants
constexpr int Bc = 16, Tc = 1536;
constexpr int T2c = 192;           // T / P1
constexpr float EPSc = 1e-5f;
constexpr float NSLOPE = 0.2f;
constexpr int MDI = 16;            // padded in-degree stride (bytes); byte15 = indeg
constexpr int MDO = 8;             // padded out-degree stride (bytes)
constexpr float L2E = 1.4426950408889634f;

// TILE = 16 output t's per gat block. 47 x-rows + ones row = 48.
constexpr int TILE = 16;
constexpr int ROWS = 48;

typedef float vf2 __attribute__((ext_vector_type(2)));

// Workspace layout (float offsets)
constexpr int OW_WEFF = 0;         // [32 k][32 f2]
constexpr int OW_CHL  = 1024;      // [32] (prep-internal; folded into c2)
constexpr int OW_CES  = 1056;      // [4 h][2] {ces,ced} interleaved
constexpr int OW_WSD  = 1064;      // [4 h][32 k][2] {wes,wed} interleaved
constexpr int OW_A2C2 = 1320;      // a2[32] | c2[32] (chl+gat-bias folded)
constexpr int OW_WFT  = 1384;      // [32 f2][32 k]  transposed weff
constexpr int OW_GRAPH= 2408;      // 417 ints packed byte graph (gat reads GLOBAL)
constexpr int OW_P    = 2825;      // [B][192][32]

// gat LDS layout (float offsets)
constexpr int L_XT  = 0;           // xT [48 c][68 v]; row 47 = ones; ROTATION-SWIZZLED
constexpr int L_WB  = 3264;        // [4 h][1088]: wb rows [16 t][68 v];
                                   //   B scratch = 4 x 256-float slices (s*272);
                                   //   after C: Y overlay [16 t][49] (wave-local)
constexpr int L_TOT = 7616;        // 30.5 KB

#define LGKM0() __asm__ volatile("s_waitcnt lgkmcnt(0)" ::: "memory")

// XT swizzle: column granule rotated by row: g' = (g + row) & 15.
__device__ __forceinline__ int xt_idx(int row, int g, int lo)
{
    return L_XT + row * 68 + (((g + row) & 15) << 2) + lo;
}

// exp2(leaky(z)) with logit pre-scaled by log2(e)
__device__ __forceinline__ float lexp2(float z)
{
    return __builtin_amdgcn_exp2f(fmaxf(z, NSLOPE * z));
}

// Butterfly sums via gfx950 permlane-swap builtins (VALU pipe; proven r6-r11).
__device__ __forceinline__ float bfly16_sum(float s)
{
#if __has_builtin(__builtin_amdgcn_permlane16_swap)
    unsigned u = __builtin_bit_cast(unsigned, s);
    auto r = __builtin_amdgcn_permlane16_swap(u, u, false, false);
    return __builtin_bit_cast(float, (unsigned)r[0]) +
           __builtin_bit_cast(float, (unsigned)r[1]);
#else
    return s + __shfl_xor(s, 16);
#endif
}

__device__ __forceinline__ float bfly32_sum(float s)
{
#if __has_builtin(__builtin_amdgcn_permlane32_swap)
    unsigned u = __builtin_bit_cast(unsigned, s);
    auto r = __builtin_amdgcn_permlane32_swap(u, u, false, false);
    return __builtin_bit_cast(float, (unsigned)r[0]) +
           __builtin_bit_cast(float, (unsigned)r[1]);
#else
    return s + __shfl_xor(s, 32);
#endif
}

// ---------------------------------------------------------------------------
// Prep (1 block). r12: a1/b1m factors hoisted to LDS (removes 16k rsqrt+mul
// from the 1024-entry weff loop — the single-block serial hot path).
// ---------------------------------------------------------------------------
__global__ void prep_kernel(const float* __restrict__ c1w,
                            const float* __restrict__ g1, const float* __restrict__ b1,
                            const float* __restrict__ m1, const float* __restrict__ v1,
                            const float* __restrict__ W,
                            const float* __restrict__ asrc, const float* __restrict__ adst,
                            const float* __restrict__ bias,
                            const float* __restrict__ g2, const float* __restrict__ b2,
                            const float* __restrict__ m2, const float* __restrict__ v2,
                            const int* __restrict__ ei, int ne, float* __restrict__ ws)
{
    const int tid = threadIdx.x;
    __shared__ float sweff[1024];
    __shared__ float schl[32];
    __shared__ float a1s[16], b1ms[16];
    __shared__ int isrcp_i[64 * MDI];
    __shared__ int outdst_i[64 * MDO];
    __shared__ int inslot[64], outslot[64];

    if (tid < 16) {
        float a1 = g1[tid] * rsqrtf(v1[tid] + EPSc);
        a1s[tid] = a1;
        b1ms[tid] = b1[tid] - a1 * m1[tid];
    }
    // graph list init (overlap with a1s barrier)
    for (int i = tid; i < 64 * MDI; i += TPB) isrcp_i[i] = 0;
    for (int i = tid; i < 64 * MDO; i += TPB) outdst_i[i] = 0;
    if (tid < 64) { inslot[tid] = 0; outslot[tid] = 0; }
    __syncthreads();

    for (int idx = tid; idx < 1024; idx += TPB) {
        int k = idx >> 5, f2 = idx & 31;
        float s = 0.f;
        #pragma unroll
        for (int f = 0; f < 16; f++)
            s = fmaf(a1s[f] * W[f * 32 + f2], c1w[f * 32 + k], s);
        ws[OW_WEFF + idx] = s;
        ws[OW_WFT + f2 * 32 + k] = s;
        sweff[idx] = s;
    }
    for (int f2 = tid; f2 < 32; f2 += TPB) {
        float s = 0.f;
        #pragma unroll
        for (int f = 0; f < 16; f++)
            s = fmaf(b1ms[f], W[f * 32 + f2], s);
        ws[OW_CHL + f2] = s;
        schl[f2] = s;
        float a2 = g2[f2] * rsqrtf(v2[f2] + EPSc);
        ws[OW_A2C2 + f2] = a2;
        // bn2 shift with gat bias AND chl (rowsum==64 exactly) folded in
        ws[OW_A2C2 + 32 + f2] = b2[f2] + a2 * (bias[f2] - m2[f2] + s);
    }

    // graph lists WITHOUT self-edges (self handled in-register in gat)
    for (int e = tid; e < ne; e += TPB) {
        int s = ei[e], d = ei[ne + e];
        if (s == d) continue;
        int pi = atomicAdd(&inslot[d], 1);
        if (pi < 15) isrcp_i[d * MDI + pi] = s;
        int po = atomicAdd(&outslot[s], 1);
        if (po < MDO) outdst_i[s * MDO + po] = d;
    }
    __syncthreads();

    // {wes,wed} interleaved pairs + {ces,ced} pairs
    if (tid < 128) {
        int k = tid >> 2, h = tid & 3;
        float s1 = 0.f, s2 = 0.f;
        for (int o = 0; o < 8; o++) {
            float wv = sweff[k * 32 + h * 8 + o];
            s1 = fmaf(asrc[h * 8 + o], wv, s1);
            s2 = fmaf(adst[h * 8 + o], wv, s2);
        }
        ws[OW_WSD + h * 64 + k * 2]     = s1;
        ws[OW_WSD + h * 64 + k * 2 + 1] = s2;
    }
    if (tid < 4) {
        float s1 = 0.f, s2 = 0.f;
        for (int o = 0; o < 8; o++) {
            float cv = schl[tid * 8 + o];
            s1 = fmaf(asrc[tid * 8 + o], cv, s1);
            s2 = fmaf(adst[tid * 8 + o], cv, s2);
        }
        ws[OW_CES + tid * 2]     = s1;
        ws[OW_CES + tid * 2 + 1] = s2;
    }
    // pack graph to bytes
    unsigned char* gb = (unsigned char*)(ws + OW_GRAPH);
    for (int i = tid; i < 64 * MDI; i += TPB) gb[i] = (unsigned char)isrcp_i[i];
    for (int i = tid; i < 64 * MDO; i += TPB) gb[1088 + i] = (unsigned char)outdst_i[i];
    __syncthreads();
    if (tid < 64) {
        int id = inslot[tid] < 15 ? inslot[tid] : 15;
        int od = outslot[tid] < MDO ? outslot[tid] : MDO;
        gb[tid * MDI + 15] = (unsigned char)id;   // indeg packed into list byte 15
        gb[1024 + tid] = (unsigned char)id;
        gb[1600 + tid] = (unsigned char)od;
    }
    __syncthreads();
    if (tid == 0) {
        int mi = 0;
        for (int d = 0; d < 64; d++) {
            int a = gb[1024 + d];
            mi = a > mi ? a : mi;
        }
        gb[1664] = (unsigned char)mi;
        gb[1665] = 0;
    }
}

// ---------------------------------------------------------------------------
// gat kernel — UNCHANGED from r11 (best measured: 49.4 µs, FETCH 12.4 MB).
// ---------------------------------------------------------------------------
__global__ __launch_bounds__(TPB, 4) void gat_kernel(
    const float* __restrict__ x,
    const float* __restrict__ wfTp,
    const float* __restrict__ cesg,
    const float* __restrict__ wsdg,
    const float* __restrict__ a2c2,
    const int* __restrict__ graphi,
    float* __restrict__ pout)
{
    __shared__ __align__(16) float sm[L_TOT];

    const int tid   = threadIdx.x;
    const int b     = blockIdx.x / 96;
    const int tile2 = blockIdx.x % 96;
    const int t0    = tile2 * TILE;

    const int h = tid >> 6, v = tid & 63;   // wave = head, lane = node

    // ---- graph loads from global, issued EARLY (latency hides under S+A) --
    const unsigned char* gbg = (const unsigned char*)graphi;
    const int4 il = *(const int4*)(gbg + v * MDI);                // in-list + indeg
    const unsigned ow = *(const unsigned*)(gbg + 1088 + v * MDO); // 4 KNN dsts
    const int mdin = __builtin_amdgcn_readfirstlane(((const int*)graphi)[416] & 0xFF);

    // ---- S: stage xT (coalesced global, swizzled LDS writes; 12 iters) ----
    for (int idx = tid; idx < ROWS * 64; idx += TPB) {
        const int vv = idx / ROWS, j = idx % ROWS;
        float val = 1.0f;
        if (j < 47) {
            const int t = t0 - 15 + j;
            val = (t >= 0 && t < Tc) ? x[(b * 64 + vv) * Tc + t] : 0.f;
        }
        sm[xt_idx(j, vv >> 2, vv & 3)] = val;
    }
    __syncthreads();   // the ONLY block-wide barrier

    const int hs = __builtin_amdgcn_readfirstlane(h);
    const vf2* wsdh = (const vf2*)(wsdg + hs * 64);   // uniform -> s_load pairs

    // ---- Phase A: es/ed convs for 16 t's, {es,ed} packed accumulators ----
    float aes[16], aed[16];
    {
        const int g = v >> 2, lo = v & 3;
        const vf2 cv = *(const vf2*)(cesg + hs * 2);
        vf2 acc2[16];
        #pragma unroll
        for (int t = 0; t < 16; t++) acc2[t] = cv;
        float xr[16];
        #pragma unroll
        for (int q = 0; q < 15; q++) xr[q] = sm[xt_idx(q, g, lo)];
        #pragma unroll
        for (int k = 0; k < 32; k++) {
            xr[(k + 15) & 15] = sm[xt_idx(k + 15, g, lo)];
            const vf2 wk = wsdh[k];                  // {wes_k, wed_k} SGPR pair
            #pragma unroll
            for (int t = 0; t < 16; t++) {
                const float xv = xr[(k + t) & 15];
                acc2[t] += (vf2){xv, xv} * wk;       // v_pk_fma_f32 (splat)
            }
        }
        #pragma unroll
        for (int t = 0; t < 16; t++) {
            aes[t] = acc2[t].x * L2E;                // exp2-domain prescale
            aed[t] = acc2[t].y * L2E;
        }
    }

    // ---- Phase B: softmax via quad-scratch wide-LDS gather (6 fences) ----
    {
        float* scr0 = &sm[L_WB + h * 1088];
        float* scr1 = &sm[L_WB + h * 1088 + 272];
        float* scr2 = &sm[L_WB + h * 1088 + 544];
        float* scr3 = &sm[L_WB + h * 1088 + 816];

        const int indeg = (int)(((unsigned)il.w) >> 24);
        const unsigned iw[4] = {(unsigned)il.x, (unsigned)il.y,
                                (unsigned)il.z, (unsigned)il.w};

        // self-edge term
        float den[16], Eself[16];
        #pragma unroll
        for (int t = 0; t < 16; t++) {
            Eself[t] = lexp2(aes[t] + aed[t]);
            den[t] = Eself[t];
        }

        // in-gather: all 16 t's staged; one drain; 4 b128 reads per edge
        *(float4*)(scr0 + v * 4) = (float4){aes[0],  aes[1],  aes[2],  aes[3]};
        *(float4*)(scr1 + v * 4) = (float4){aes[4],  aes[5],  aes[6],  aes[7]};
        *(float4*)(scr2 + v * 4) = (float4){aes[8],  aes[9],  aes[10], aes[11]};
        *(float4*)(scr3 + v * 4) = (float4){aes[12], aes[13], aes[14], aes[15]};
        LGKM0();
        #pragma unroll
        for (int e = 0; e < 15; e++) {
            if (e < mdin) {                  // wave-uniform bound
                const int s = (int)((iw[e >> 2] >> ((e & 3) * 8)) & 0xFF);
                const float4 ea = *(const float4*)(scr0 + s * 4);
                const float4 eb = *(const float4*)(scr1 + s * 4);
                const float4 ec = *(const float4*)(scr2 + s * 4);
                const float4 ed = *(const float4*)(scr3 + s * 4);
                const float valid = (e < indeg) ? 1.f : 0.f;
                den[0]  += valid * lexp2(ea.x + aed[0]);
                den[1]  += valid * lexp2(ea.y + aed[1]);
                den[2]  += valid * lexp2(ea.z + aed[2]);
                den[3]  += valid * lexp2(ea.w + aed[3]);
                den[4]  += valid * lexp2(eb.x + aed[4]);
                den[5]  += valid * lexp2(eb.y + aed[5]);
                den[6]  += valid * lexp2(eb.z + aed[6]);
                den[7]  += valid * lexp2(eb.w + aed[7]);
                den[8]  += valid * lexp2(ec.x + aed[8]);
                den[9]  += valid * lexp2(ec.y + aed[9]);
                den[10] += valid * lexp2(ec.z + aed[10]);
                den[11] += valid * lexp2(ec.w + aed[11]);
                den[12] += valid * lexp2(ed.x + aed[12]);
                den[13] += valid * lexp2(ed.y + aed[13]);
                den[14] += valid * lexp2(ed.z + aed[14]);
                den[15] += valid * lexp2(ed.w + aed[15]);
            }
        }
        LGKM0();

        float rden[16], wb[16];
        #pragma unroll
        for (int t = 0; t < 16; t++) {
            float r = __builtin_amdgcn_rcpf(den[t]);
            r = r * (2.f - den[t] * r);
            rden[t] = r;
            wb[t] = Eself[t] * r;
        }

        // out-gather: 2 rounds x 8 t's; {ed,ed,rden,rden} quads in 4 scratches
        #pragma unroll
        for (int r2 = 0; r2 < 2; r2++) {
            const int tb = r2 * 8;
            *(float4*)(scr0 + v * 4) = (float4){aed[tb + 0], aed[tb + 1],
                                                rden[tb + 0], rden[tb + 1]};
            *(float4*)(scr1 + v * 4) = (float4){aed[tb + 2], aed[tb + 3],
                                                rden[tb + 2], rden[tb + 3]};
            *(float4*)(scr2 + v * 4) = (float4){aed[tb + 4], aed[tb + 5],
                                                rden[tb + 4], rden[tb + 5]};
            *(float4*)(scr3 + v * 4) = (float4){aed[tb + 6], aed[tb + 7],
                                                rden[tb + 6], rden[tb + 7]};
            LGKM0();
            #pragma unroll
            for (int j = 0; j < 4; j++) {
                const int d = (int)((ow >> (j * 8)) & 0xFF);
                const float4 g0 = *(const float4*)(scr0 + d * 4);
                const float4 g1 = *(const float4*)(scr1 + d * 4);
                const float4 g2 = *(const float4*)(scr2 + d * 4);
                const float4 g3 = *(const float4*)(scr3 + d * 4);
                wb[tb + 0] = fmaf(lexp2(aes[tb + 0] + g0.x), g0.z, wb[tb + 0]);
                wb[tb + 1] = fmaf(lexp2(aes[tb + 1] + g0.y), g0.w, wb[tb + 1]);
                wb[tb + 2] = fmaf(lexp2(aes[tb + 2] + g1.x), g1.z, wb[tb + 2]);
                wb[tb + 3] = fmaf(lexp2(aes[tb + 3] + g1.y), g1.w, wb[tb + 3]);
                wb[tb + 4] = fmaf(lexp2(aes[tb + 4] + g2.x), g2.z, wb[tb + 4]);
                wb[tb + 5] = fmaf(lexp2(aes[tb + 5] + g2.y), g2.w, wb[tb + 5]);
                wb[tb + 6] = fmaf(lexp2(aes[tb + 6] + g3.x), g3.z, wb[tb + 6]);
                wb[tb + 7] = fmaf(lexp2(aes[tb + 7] + g3.y), g3.w, wb[tb + 7]);
            }
            LGKM0();
        }

        // wb stores land after scratch is dead (all reads drained)
        #pragma unroll
        for (int t = 0; t < 16; t++)
            sm[L_WB + h * 1088 + t * 68 + v] = wb[t];
    }
    LGKM0();   // wave-local drain before C reads own-head wb rows

    // ---- Phase C: y[t,c] = sum_v wb[t,v]*xT[c,v], 2 reps of 8 t-rows ----
    {
        const int cg = v & 7;
        const int th = (v >> 3) & 1;
        const int kq = v >> 4;

        #pragma unroll
        for (int rep = 0; rep < 2; rep++) {
            vf2 yp[4][6];
            #pragma unroll
            for (int i = 0; i < 4; i++)
                #pragma unroll
                for (int q = 0; q < 6; q++) yp[i][q] = (vf2){0.f, 0.f};

            const float* wbbase = &sm[L_WB + h * 1088 + (rep * 8 + th * 4) * 68];
            #pragma unroll
            for (int v4 = 0; v4 < 4; v4++) {
                const int vcol = kq * 16 + v4 * 4;
                float4 wrow[4];
                #pragma unroll
                for (int i = 0; i < 4; i++)
                    wrow[i] = *(const float4*)(wbbase + i * 68 + vcol);
                #pragma unroll
                for (int q = 0; q < 6; q++) {
                    const int row = cg * 6 + q;
                    const int mg = ((kq * 4 + v4 + row) & 15) << 2;   // swizzled
                    const float4 x4 = *(const float4*)(&sm[L_XT + row * 68 + mg]);
                    const vf2 x01 = (vf2){x4.x, x4.y}, x23 = (vf2){x4.z, x4.w};
                    #pragma unroll
                    for (int i = 0; i < 4; i++) {
                        const vf2 w01 = (vf2){wrow[i].x, wrow[i].y};
                        const vf2 w23 = (vf2){wrow[i].z, wrow[i].w};
                        yp[i][q] += w01 * x01;          // v_pk_fma_f32
                        yp[i][q] += w23 * x23;
                    }
                }
            }
            float ya[4][6];
            #pragma unroll
            for (int i = 0; i < 4; i++)
                #pragma unroll
                for (int q = 0; q < 6; q++) {
                    float s = yp[i][q].x + yp[i][q].y;
                    ya[i][q] = bfly32_sum(bfly16_sum(s));
                }
            // write Y row rep*8 + th*4 + kq, cols cg*6..cg*6+5 (stride 49)
            float* yw = &sm[L_WB + h * 1088 + (rep * 8 + th * 4 + kq) * 49 + cg * 6];
            #pragma unroll
            for (int q = 0; q < 6; q++) {
                float a01 = (kq & 1) ? ya[1][q] : ya[0][q];
                float a23 = (kq & 1) ? ya[3][q] : ya[2][q];
                yw[q] = (kq & 2) ? a23 : a01;
            }
        }
    }
    LGKM0();   // wave-local: D reads only own-head Y rows

    // ---- Phase D+E fused (wave-local): g -> bn2+elu -> pool8, 2 outputs ----
    {
        const int t = v >> 3, o = v & 7;
        const int f2d = h * 8 + o;
        const float4* wf4 = (const float4*)(wfTp + f2d * 32);
        const float a2 = a2c2[f2d], c2 = a2c2[32 + f2d];

        #pragma unroll
        for (int po = 0; po < 2; po++) {
            const int tt = po * 8 + t;
            const float* yr = &sm[L_WB + h * 1088 + tt * 49];
            float acc = 0.f;                 // chl folded into c2 (rowsum==64)
            #pragma unroll
            for (int k4 = 0; k4 < 8; k4++) {
                const float4 w = wf4[k4];
                acc = fmaf(w.x, yr[tt + 4 * k4 + 0],
                      fmaf(w.y, yr[tt + 4 * k4 + 1],
                      fmaf(w.z, yr[tt + 4 * k4 + 2],
                      fmaf(w.w, yr[tt + 4 * k4 + 3], acc))));
            }
            float y = fmaf(a2, acc * (1.f / 64.f), c2);
            y = y > 0.f ? y : __expf(y) - 1.f;
            y += __shfl_xor(y, 8);
            y = bfly32_sum(bfly16_sum(y));
            if (v < 8)
                pout[(b * T2c + tile2 * 2 + po) * 32 + h * 8 + v] = y * 0.125f;
        }
    }
}

// ---------------------------------------------------------------------------
// conv3 v2: grid 128 blocks (16 b x 8 chunks of 24 t2), 192 threads.
// pl staged TRANSPOSED plT[f2i][42] so per-thread 19-float windows are
// contiguous -> ds_read2_b64/b128 merging (~3.5x fewer DS insts than the
// scalar [r][f2] layout). 4-outputs/thread blocking (tb = 4g, 16B-friendly).
// ---------------------------------------------------------------------------
__global__ __launch_bounds__(192) void conv3_kernel(const float* __restrict__ pp,
                                                    const float* __restrict__ w3,
                                                    const float* __restrict__ g3,
                                                    const float* __restrict__ b3,
                                                    const float* __restrict__ m3,
                                                    const float* __restrict__ v3,
                                                    float* __restrict__ outp)
{
    __shared__ __align__(16) float plT[32 * 42];   // [f2i][r], r in [0,39)
    __shared__ float q[24 * 32];                   // conv+bn+elu results
    const int tid = threadIdx.x;
    const int b = blockIdx.x >> 3, cc = blockIdx.x & 7;   // chunk of 24 t2

    // stage transposed: stage r = p[b][cc*24 - 7 + r][f2]
    for (int idx = tid; idx < 39 * 32; idx += 192) {
        int r = idx >> 5, f2 = idx & 31;
        int tog = cc * 24 - 7 + r;
        plT[f2 * 42 + r] = (tog >= 0 && tog < T2c) ? pp[(b * T2c + tog) * 32 + f2] : 0.f;
    }
    __syncthreads();

    const int f2o = tid & 31, grp = tid >> 5;   // grp in [0,6): 4 t2-outputs
    const int tb = grp * 4;
    float acc[4] = { 0.f, 0.f, 0.f, 0.f };
    for (int f2i = 0; f2i < 32; f2i++) {
        float seg[19];
        const float* base = &plT[f2i * 42 + tb];
        #pragma unroll
        for (int r = 0; r < 19; r++) seg[r] = base[r];   // contiguous -> merged
        const float4* wrow = (const float4*)(w3 + (f2o * 32 + f2i) * 16);
        #pragma unroll
        for (int k4 = 0; k4 < 4; k4++) {
            const float4 w4 = wrow[k4];
            #pragma unroll
            for (int j = 0; j < 4; j++) {
                acc[j] = fmaf(seg[j + k4 * 4 + 0], w4.x,
                         fmaf(seg[j + k4 * 4 + 1], w4.y,
                         fmaf(seg[j + k4 * 4 + 2], w4.z,
                         fmaf(seg[j + k4 * 4 + 3], w4.w, acc[j]))));
            }
        }
    }
    const float a3 = g3[f2o] * rsqrtf(v3[f2o] + EPSc);
    const float c3 = b3[f2o] - a3 * m3[f2o];
    #pragma unroll
    for (int j = 0; j < 4; j++) {
        float y = fmaf(a3, acc[j], c3);
        y = y > 0.f ? y : __expf(y) - 1.f;
        q[(tb + j) * 32 + f2o] = y;
    }
    __syncthreads();
    // pool4: 24 t2 -> 6 t4 outputs per block; 6*32 = 192 = one per thread
    {
        int t4l = tid >> 5, f2 = tid & 31;
        int r0 = t4l * 4;
        float s = q[r0 * 32 + f2] + q[(r0 + 1) * 32 + f2] +
                  q[(r0 + 2) * 32 + f2] + q[(r0 + 3) * 32 + f2];
        outp[(b * 32 + f2) * 48 + cc * 6 + t4l] = s * 0.25f;
    }
}

// ---------------------------------------------------------------------------
extern "C" void kernel_launch(void* const* d_in, const int* in_sizes, int n_in,
                              void* d_out, int out_size, void* d_ws, size_t ws_size,
                              hipStream_t stream)
{
    const float* x    = (const float*)d_in[0];
    const float* c1w  = (const float*)d_in[1];
    const float* g1   = (const float*)d_in[2];
    const float* b1   = (const float*)d_in[3];
    const float* m1   = (const float*)d_in[4];
    const float* v1   = (const float*)d_in[5];
    const float* W    = (const float*)d_in[6];
    const float* asrc = (const float*)d_in[7];
    const float* adst = (const float*)d_in[8];
    const float* bias = (const float*)d_in[9];
    const float* g2   = (const float*)d_in[10];
    const float* b2   = (const float*)d_in[11];
    const float* m2   = (const float*)d_in[12];
    const float* v2   = (const float*)d_in[13];
    const float* w3   = (const float*)d_in[14];
    const float* g3   = (const float*)d_in[15];
    const float* b3   = (const float*)d_in[16];
    const float* m3   = (const float*)d_in[17];
    const float* v3   = (const float*)d_in[18];
    const int*   ei   = (const int*)d_in[19];
    const int    ne   = in_sizes[19] / 2;

    float* ws = (float*)d_ws;

    prep_kernel<<<1, TPB, 0, stream>>>(c1w, g1, b1, m1, v1, W, asrc, adst,
                                       bias, g2, b2, m2, v2, ei, ne, ws);

    gat_kernel<<<Bc * 96, TPB, 0, stream>>>(x,
                                            ws + OW_WFT,
                                            ws + OW_CES,
                                            ws + OW_WSD,
                                            ws + OW_A2C2,
                                            (const int*)(ws + OW_GRAPH),
                                            ws + OW_P);

    conv3_kernel<<<Bc * 8, 192, 0, stream>>>(ws + OW_P, w3, g3, b3, m3, v3,
                                             (float*)d_out);
}